// Round 1
// baseline (2934.760 us; speedup 1.0000x reference)
//
#include <hip/hip_runtime.h>
#include <hip/hip_bf16.h>
#include <stdint.h>

// Problem constants
#define P 2048
#define V 50257
#define D 4096
#define CAP 512            // candidate slots per row (fp8 margin is wider)
#define MARGIN 1.0e-2f     // ~22 sigma of fp8 e4m3 dot error (sigma ~4.5e-4)

#define BM 128
#define BN 128
#define BK 32              // bf16 slow-path K-step
#define BKF 128            // fp8 fast-path K-step (one MFMA K=128 per frag)

using frag_ab = __attribute__((ext_vector_type(8))) short;  // 8 bf16 (4 VGPRs)
using frag_cd = __attribute__((ext_vector_type(4))) float;  // 4 fp32 acc
using i32x4   = __attribute__((ext_vector_type(4))) int;
using i32x8   = __attribute__((ext_vector_type(8))) int;

__device__ __forceinline__ unsigned short f2bf(float f) {
    __hip_bfloat16 h = __float2bfloat16(f);
    return *(unsigned short*)&h;
}

// OCP e4m3 saturating RNE conversion (hand-rolled: no hip_fp8.h dependency)
__device__ __forceinline__ unsigned char f2e4m3(float f) {
    uint32_t u = __float_as_uint(f);
    unsigned char sign = (unsigned char)((u >> 24) & 0x80u);
    uint32_t a = u & 0x7FFFFFFFu;
    if (a >= 0x43E00000u) return sign | 0x7E;        // >=448 -> clamp to 448
    if (a < 0x3C800000u) {                           // <2^-6 -> subnormal
        float af = __uint_as_float(a);
        int q = __float2int_rn(af * 512.0f);         // RNE onto 2^-9 grid, 0..8
        return sign | (unsigned char)q;              // q==8 -> 0x08 == 2^-6
    }
    uint32_t r = a + 0x0007FFFFu + ((a >> 20) & 1u); // RNE into 3-bit mantissa
    int eb = (int)(r >> 23) - 127 + 7;
    uint32_t m = (r >> 20) & 7u;
    return sign | (unsigned char)((eb << 3) | m);
}

// monotone key: order of key == order of float (incl. negatives)
__device__ __forceinline__ uint32_t fkey(float f) {
    uint32_t u = __float_as_uint(f);
    return (u & 0x80000000u) ? ~u : (u | 0x80000000u);
}
__device__ __forceinline__ float key2f(uint32_t k) {
    uint32_t u = (k & 0x80000000u) ? (k ^ 0x80000000u) : ~k;
    return __uint_as_float(u);
}

#define GLD_LDS16(g, l) __builtin_amdgcn_global_load_lds(                      \
    (const __attribute__((address_space(1))) void*)(g),                        \
    (__attribute__((address_space(3))) void*)(l), 16, 0, 0)

// ---------------- normalize embeddings -> fp8 (x256), init state ------------
__global__ __launch_bounds__(256) void normalize_e8(
        const float* __restrict__ E, unsigned char* __restrict__ A8,
        unsigned long long* __restrict__ packmax, int* __restrict__ cnt) {
    const int p = blockIdx.x;
    const int t = threadIdx.x;
    const float* row = E + (size_t)p * D;

    float4 vals[4];
    float ss = 0.f;
#pragma unroll
    for (int c = 0; c < 4; c++) {
        vals[c] = ((const float4*)row)[c * 256 + t];
        ss += vals[c].x * vals[c].x + vals[c].y * vals[c].y
            + vals[c].z * vals[c].z + vals[c].w * vals[c].w;
    }
#pragma unroll
    for (int o = 1; o < 64; o <<= 1) ss += __shfl_xor(ss, o);
    __shared__ float wss[4];
    if ((t & 63) == 0) wss[t >> 6] = ss;
    __syncthreads();
    float tot = wss[0] + wss[1] + wss[2] + wss[3];
    float s = 256.0f / fmaxf(sqrtf(tot), 1e-8f);   // x256 pre-scale into e4m3 range

    unsigned char* dst = A8 + (size_t)p * D;
#pragma unroll
    for (int c = 0; c < 4; c++) {
        float4 v = vals[c];
        uint32_t b = (uint32_t)f2e4m3(v.x * s)
                   | ((uint32_t)f2e4m3(v.y * s) << 8)
                   | ((uint32_t)f2e4m3(v.z * s) << 16)
                   | ((uint32_t)f2e4m3(v.w * s) << 24);
        ((uint32_t*)dst)[c * 256 + t] = b;
    }
    if (t == 0) { packmax[p] = 0ull; cnt[p] = 0; }
}

// ---------------- normalize table row -> fp8 (x256) -------------------------
__global__ __launch_bounds__(256) void normalize_t8(
        const float* __restrict__ T, unsigned char* __restrict__ T8) {
    const int v = blockIdx.x;
    const int t = threadIdx.x;
    const float* row = T + (size_t)v * D;

    float4 vals[4];
    float ss = 0.f;
#pragma unroll
    for (int c = 0; c < 4; c++) {
        vals[c] = ((const float4*)row)[c * 256 + t];
        ss += vals[c].x * vals[c].x + vals[c].y * vals[c].y
            + vals[c].z * vals[c].z + vals[c].w * vals[c].w;
    }
#pragma unroll
    for (int o = 1; o < 64; o <<= 1) ss += __shfl_xor(ss, o);
    __shared__ float wss[4];
    if ((t & 63) == 0) wss[t >> 6] = ss;
    __syncthreads();
    float tot = wss[0] + wss[1] + wss[2] + wss[3];
    float s = 256.0f / fmaxf(sqrtf(tot), 1e-8f);

    unsigned char* dst = T8 + (size_t)v * D;
#pragma unroll
    for (int c = 0; c < 4; c++) {
        float4 x = vals[c];
        uint32_t b = (uint32_t)f2e4m3(x.x * s)
                   | ((uint32_t)f2e4m3(x.y * s) << 8)
                   | ((uint32_t)f2e4m3(x.z * s) << 16)
                   | ((uint32_t)f2e4m3(x.w * s) << 24);
        ((uint32_t*)dst)[c * 256 + t] = b;
    }
}

// ---------------- FAST PATH: MX-fp8 K=128 MFMA GEMM + argmax epilogue -------
// m148 port of the m97 structure: 128x128 tile, BKF=128, global_load_lds w16,
// 2-barrier loop. Scales all 1.0 (0x7F e8m0); data pre-scaled by 256 per side,
// scores rescaled by 2^-16 in the epilogue.
// LDS swizzle (G4 fix for 128B rows): LDS[row][j16] = G[row][j16 ^ (row&7)],
// applied on the GLOBAL source (gload_lds dest must stay linear, rule #21)
// and inverted on the fragment reads.
__global__ __launch_bounds__(256) void gemm_fp8_argmax(
        const unsigned char* __restrict__ A8,   // [P][D] fp8 (normalized*256)
        const unsigned char* __restrict__ T8,   // [V][D] fp8 (normalized*256)
        unsigned long long* __restrict__ packmax,
        int* __restrict__ cnt, int* __restrict__ cand) {
    __shared__ __align__(16) unsigned char As[BM * BKF];  // 16 KB
    __shared__ __align__(16) unsigned char Bs[BN * BKF];  // 16 KB

    const int t = threadIdx.x;
    const int m0 = blockIdx.x * BM;   // x fastest: 16 M-blocks share a B tile
    const int v0 = blockIdx.y * BN;
    const int lane = t & 63;
    const int w = t >> 6;
    const int wm = w & 1, wn = w >> 1;
    const int l15 = lane & 15, lq = lane >> 4;

    // staging: wave w stages rows [w*32, w*32+32) of A and B; 4 GLDs each.
    // GLD g writes 1024B at lds_base + lane*16 -> slot row = w*32+g*8+(lane>>3),
    // slot 16B-chunk = lane&7. Pre-swizzled source chunk = (lane&7) ^ (row&7).
    const int sr = lane >> 3;                 // row-within-8 (== row&7 of slot)
    const int sj = (lane & 7) ^ sr;           // swizzled source chunk
    const unsigned char* gA = A8 + (size_t)(m0 + w * 32 + sr) * D + sj * 16;
    const unsigned char* gB[4];
#pragma unroll
    for (int g = 0; g < 4; g++) {
        int r = v0 + w * 32 + g * 8 + sr;
        if (r > V - 1) r = V - 1;
        gB[g] = T8 + (size_t)r * D + sj * 16;
    }
    unsigned char* lA = As + w * 4096;
    unsigned char* lB = Bs + w * 4096;

    frag_cd acc[4][4] = {};

    for (int k0 = 0; k0 < D; k0 += BKF) {
        __syncthreads();   // previous iteration's fragment reads done
#pragma unroll
        for (int g = 0; g < 4; g++) {
            GLD_LDS16(gA + (size_t)g * 8 * D + k0, lA + g * 1024);
            GLD_LDS16(gB[g] + k0, lB + g * 1024);
        }
        __syncthreads();   // compiler drains vmcnt(0) before s_barrier

        // fragment: lane holds row=l15(+16i+64wm), k = lq*32..lq*32+31
        i32x8 af[4], bfr[4];
#pragma unroll
        for (int i = 0; i < 4; i++) {
            const int row = wm * 64 + i * 16 + l15;
            const int sw = (row & 7) << 4;
            const int base = row * BKF;
            i32x4 h0 = *(const i32x4*)&As[base + ((lq * 32) ^ sw)];
            i32x4 h1 = *(const i32x4*)&As[base + ((lq * 32 + 16) ^ sw)];
            af[i] = __builtin_shufflevector(h0, h1, 0, 1, 2, 3, 4, 5, 6, 7);
        }
#pragma unroll
        for (int j = 0; j < 4; j++) {
            const int row = wn * 64 + j * 16 + l15;
            const int sw = (row & 7) << 4;
            const int base = row * BKF;
            i32x4 h0 = *(const i32x4*)&Bs[base + ((lq * 32) ^ sw)];
            i32x4 h1 = *(const i32x4*)&Bs[base + ((lq * 32 + 16) ^ sw)];
            bfr[j] = __builtin_shufflevector(h0, h1, 0, 1, 2, 3, 4, 5, 6, 7);
        }
#pragma unroll
        for (int i = 0; i < 4; i++)
#pragma unroll
            for (int j = 0; j < 4; j++)
                acc[i][j] = __builtin_amdgcn_mfma_scale_f32_16x16x128_f8f6f4(
                    af[i], bfr[j], acc[i][j],
                    0, 0,                      // cbsz=fp8(e4m3), blgp=fp8(e4m3)
                    0, 0x7F7F7F7F,             // opsel_a, scale_a = 1.0 (e8m0)
                    0, 0x7F7F7F7F);            // opsel_b, scale_b = 1.0
    }

    // epilogue: rescale 2^-16, per embedding-row running max + candidate append
#pragma unroll
    for (int i = 0; i < 4; i++) {
#pragma unroll
        for (int r = 0; r < 4; r++) {
            const int p = m0 + wm * 64 + i * 16 + lq * 4 + r;  // C row = lq*4+reg
            float sc[4];
            int nidx[4];
            unsigned long long best = 0ull;
#pragma unroll
            for (int j = 0; j < 4; j++) {
                int nl = wn * 64 + j * 16 + l15;               // C col = lane&15
                int n = v0 + nl;
                float s = -2.0f;
                if (n < V) s = acc[i][j][r] * 0x1p-16f;
                sc[j] = s; nidx[j] = n;
                if (n < V) {
                    unsigned long long pk =
                        ((unsigned long long)fkey(s) << 32) |
                        (unsigned long long)(0xFFFFFFFFu - (uint32_t)n);
                    if (pk > best) best = pk;
                }
            }
#pragma unroll
            for (int o = 1; o < 16; o <<= 1) {
                unsigned long long other = __shfl_xor(best, o);
                if (other > best) best = other;
            }
            unsigned long long oldpk = 0ull;
            if (l15 == 0) oldpk = atomicMax(packmax + p, best);
            oldpk = __shfl(oldpk, lane & 48);   // broadcast from group leader
            unsigned long long merged = best > oldpk ? best : oldpk;
            float thr = key2f((uint32_t)(merged >> 32)) - MARGIN;
#pragma unroll
            for (int j = 0; j < 4; j++) {
                if (nidx[j] < V && sc[j] >= thr) {
                    int slot = atomicAdd(cnt + p, 1);
                    if (slot < CAP) cand[p * CAP + slot] = nidx[j];
                }
            }
        }
    }
}

// ---------------- bf16 normalize_e (slow path only) -------------------------
__global__ __launch_bounds__(256) void normalize_e(
        const float* __restrict__ E, unsigned short* __restrict__ Abf,
        unsigned long long* __restrict__ packmax, int* __restrict__ cnt) {
    const int p = blockIdx.x;
    const int t = threadIdx.x;
    const float* row = E + (size_t)p * D;

    float4 vals[4];
    float ss = 0.f;
#pragma unroll
    for (int c = 0; c < 4; c++) {
        vals[c] = ((const float4*)row)[c * 256 + t];
        ss += vals[c].x * vals[c].x + vals[c].y * vals[c].y
            + vals[c].z * vals[c].z + vals[c].w * vals[c].w;
    }
#pragma unroll
    for (int o = 1; o < 64; o <<= 1) ss += __shfl_xor(ss, o);
    __shared__ float wss[4];
    if ((t & 63) == 0) wss[t >> 6] = ss;
    __syncthreads();
    float tot = wss[0] + wss[1] + wss[2] + wss[3];
    float inv = 1.0f / fmaxf(sqrtf(tot), 1e-8f);

    unsigned short* dst = Abf + (size_t)p * D;
#pragma unroll
    for (int c = 0; c < 4; c++) {
        float4 v = vals[c];
        uint2 st;
        st.x = (uint32_t)f2bf(v.x * inv) | ((uint32_t)f2bf(v.y * inv) << 16);
        st.y = (uint32_t)f2bf(v.z * inv) | ((uint32_t)f2bf(v.w * inv) << 16);
        ((uint2*)dst)[c * 256 + t] = st;
    }
    if (t == 0) { packmax[p] = 0ull; cnt[p] = 0; }
}

// ---------------- SLOW PATH (ws too small): fp32-table on-the-fly GEMM ------
__global__ __launch_bounds__(256) void gemm_argmax(
        const unsigned short* __restrict__ Abf,   // [P][D] bf16 (normalized)
        const float* __restrict__ T,              // [V][D] fp32
        unsigned long long* __restrict__ packmax,
        int* __restrict__ cnt, int* __restrict__ cand) {
    __shared__ unsigned short As[BM * BK];
    __shared__ unsigned short Bs[BN * BK];
    __shared__ float invt[BN];

    const int t = threadIdx.x;
    const int m0 = blockIdx.x * BM;
    const int v0 = blockIdx.y * BN;
    const int lane = t & 63;
    const int wm = (t >> 6) & 1, wn = (t >> 6) >> 1;
    const int l15 = lane & 15, lq = lane >> 4;
    const int r0 = t >> 2, q0 = t & 3;

    frag_cd acc[4][4] = {};
    float ssq0 = 0.f, ssq1 = 0.f;

    for (int k0 = 0; k0 < D; k0 += BK) {
        uint4 areg[2];
        float4 b0[2], b1[2];
#pragma unroll
        for (int pass = 0; pass < 2; pass++) {
            int row = pass * 64 + r0;
            areg[pass] = *(const uint4*)(Abf + (size_t)(m0 + row) * D + k0 + q0 * 8);
            int v = v0 + row;
            if (v < V) {
                const float* src = T + (size_t)v * D + k0 + q0 * 8;
                b0[pass] = *(const float4*)src;
                b1[pass] = *(const float4*)(src + 4);
            } else {
                b0[pass] = float4{0.f, 0.f, 0.f, 0.f};
                b1[pass] = float4{0.f, 0.f, 0.f, 0.f};
            }
        }
        __syncthreads();
#pragma unroll
        for (int pass = 0; pass < 2; pass++) {
            *(uint4*)&As[(size_t)(pass * 256 + t) * 8] = areg[pass];
            float4 x = b0[pass], y = b1[pass];
            float s = x.x * x.x + x.y * x.y + x.z * x.z + x.w * x.w
                    + y.x * y.x + y.y * y.y + y.z * y.z + y.w * y.w;
            if (pass == 0) ssq0 += s; else ssq1 += s;
            uint4 bv;
            bv.x = (uint32_t)f2bf(x.x) | ((uint32_t)f2bf(x.y) << 16);
            bv.y = (uint32_t)f2bf(x.z) | ((uint32_t)f2bf(x.w) << 16);
            bv.z = (uint32_t)f2bf(y.x) | ((uint32_t)f2bf(y.y) << 16);
            bv.w = (uint32_t)f2bf(y.z) | ((uint32_t)f2bf(y.w) << 16);
            *(uint4*)&Bs[(size_t)(pass * 256 + t) * 8] = bv;
        }
        __syncthreads();

        frag_ab af[4], bf[4];
#pragma unroll
        for (int i = 0; i < 4; i++)
            af[i] = *(const frag_ab*)&As[(wm * 64 + i * 16 + l15) * BK + lq * 8];
#pragma unroll
        for (int j = 0; j < 4; j++)
            bf[j] = *(const frag_ab*)&Bs[(wn * 64 + j * 16 + l15) * BK + lq * 8];
#pragma unroll
        for (int i = 0; i < 4; i++)
#pragma unroll
            for (int j = 0; j < 4; j++)
                acc[i][j] = __builtin_amdgcn_mfma_f32_16x16x32_bf16(af[i], bf[j], acc[i][j], 0, 0, 0);
    }

    ssq0 += __shfl_xor(ssq0, 1); ssq0 += __shfl_xor(ssq0, 2);
    ssq1 += __shfl_xor(ssq1, 1); ssq1 += __shfl_xor(ssq1, 2);
    __syncthreads();
    if ((t & 3) == 0) {
        invt[r0]      = ssq0 > 0.f ? rsqrtf(ssq0) : 0.f;
        invt[64 + r0] = ssq1 > 0.f ? rsqrtf(ssq1) : 0.f;
    }
    __syncthreads();

#pragma unroll
    for (int i = 0; i < 4; i++) {
#pragma unroll
        for (int r = 0; r < 4; r++) {
            const int p = m0 + wm * 64 + i * 16 + lq * 4 + r;
            float sc[4];
            int nidx[4];
            unsigned long long best = 0ull;
#pragma unroll
            for (int j = 0; j < 4; j++) {
                int nl = wn * 64 + j * 16 + l15;
                int n = v0 + nl;
                float s = -2.0f;
                if (n < V) s = acc[i][j][r] * invt[nl];
                sc[j] = s; nidx[j] = n;
                if (n < V) {
                    unsigned long long pk =
                        ((unsigned long long)fkey(s) << 32) |
                        (unsigned long long)(0xFFFFFFFFu - (uint32_t)n);
                    if (pk > best) best = pk;
                }
            }
#pragma unroll
            for (int o = 1; o < 16; o <<= 1) {
                unsigned long long other = __shfl_xor(best, o);
                if (other > best) best = other;
            }
            unsigned long long oldpk = 0ull;
            if (l15 == 0) oldpk = atomicMax(packmax + p, best);
            oldpk = __shfl(oldpk, lane & 48);
            unsigned long long merged = best > oldpk ? best : oldpk;
            float thr = key2f((uint32_t)(merged >> 32)) - MARGIN;
#pragma unroll
            for (int j = 0; j < 4; j++) {
                if (nidx[j] < V && sc[j] >= thr) {
                    int slot = atomicAdd(cnt + p, 1);
                    if (slot < CAP) cand[p * CAP + slot] = nidx[j];
                }
            }
        }
    }
}

// ---------------- exact fp64 rescore of candidates (wave-parallel) ----------
__global__ __launch_bounds__(256) void rescore(
        const float* __restrict__ E, const float* __restrict__ T,
        const unsigned long long* __restrict__ packmax,
        const int* __restrict__ cnt, const int* __restrict__ cand,
        int* __restrict__ out) {
    const int p = blockIdx.x;
    const int t = threadIdx.x;
    const int w = t >> 6, lane = t & 63;
    const float* e = E + (size_t)p * D;

    const int c = cnt[p];
    const bool overflow = c > CAP;
    const int ncand = overflow ? 0 : c;

    unsigned long long pk = packmax[p];
    const int pv = (int)(0xFFFFFFFFu - (uint32_t)(pk & 0xFFFFFFFFull));

    double best_s = -3.0;
    int best_v = 0x7FFFFFFF;

    auto evalw = [&](int v) -> double {   // whole-wave fp64 cosine
        const float* tr = T + (size_t)v * D;
        double dot = 0.0, ss = 0.0;
        for (int i = lane; i < D; i += 64) {
            double ev = e[i], tv = tr[i];
            dot += ev * tv;
            ss  += tv * tv;
        }
#pragma unroll
        for (int o = 1; o < 64; o <<= 1) {
            dot += __shfl_xor(dot, o);
            ss  += __shfl_xor(ss, o);
        }
        return dot / fmax(sqrt(ss), 1e-8);
    };
    auto consider = [&](int v, double s) {
        if (s > best_s || (s == best_s && v < best_v)) { best_s = s; best_v = v; }
    };

    if (!overflow) {
        const int total = ncand + 1;
        for (int idx = w; idx < total; idx += 4) {
            int v = (idx == 0) ? pv : cand[p * CAP + idx - 1];
            consider(v, evalw(v));
        }
    } else {
        // statistical never-case safety net: exact full scan
        for (int v = w; v < V; v += 4) consider(v, evalw(v));
    }

    __shared__ double bs[4];
    __shared__ int bv[4];
    if (lane == 0) { bs[w] = best_s; bv[w] = best_v; }
    __syncthreads();
    if (t == 0) {
        double s = bs[0]; int v = bv[0];
#pragma unroll
        for (int i = 1; i < 4; i++)
            if (bs[i] > s || (bs[i] == s && bv[i] < v)) { s = bs[i]; v = bv[i]; }
        out[p] = v;
    }
}

// ---------------- Launch ----------------------------------------------------
extern "C" void kernel_launch(void* const* d_in, const int* in_sizes, int n_in,
                              void* d_out, int out_size, void* d_ws, size_t ws_size,
                              hipStream_t stream) {
    const float* E = (const float*)d_in[0];   // [2048,4096] fp32
    const float* T = (const float*)d_in[1];   // [50257,4096] fp32
    int* out = (int*)d_out;                   // [2048] int32 ids

    char* ws = (char*)d_ws;

    // fast-path ws layout (fp8):
    //  0           : T8       50257*4096   = 205,852,672
    //  205,852,672 : A8       2048*4096    =   8,388,608
    //  214,241,280 : packmax  2048*8       =      16,384
    //  214,257,664 : cnt      2048*4       =       8,192
    //  214,265,856 : cand     2048*512*4   =   4,194,304
    //  total: 218,460,160
    const size_t FAST_WS = 218460160ull;

    if (ws_size >= FAST_WS) {
        unsigned char* T8 = (unsigned char*)ws;
        unsigned char* A8 = (unsigned char*)(ws + 205852672ull);
        unsigned long long* packmax = (unsigned long long*)(ws + 214241280ull);
        int* cnt  = (int*)(ws + 214257664ull);
        int* cand = (int*)(ws + 214265856ull);

        normalize_e8<<<P, 256, 0, stream>>>(E, A8, packmax, cnt);
        normalize_t8<<<V, 256, 0, stream>>>(T, T8);
        dim3 g1(P / BM, (V + BN - 1) / BN);   // x fastest: 16 M-blocks share B tile
        gemm_fp8_argmax<<<g1, 256, 0, stream>>>(A8, T8, packmax, cnt, cand);
        rescore<<<P, 256, 0, stream>>>(E, T, packmax, cnt, cand, out);
    } else {
        // slow path (ws >= ~21 MB): on-the-fly fp32 table conversion, bf16 MFMA
        unsigned short* Abf = (unsigned short*)ws;
        unsigned long long* packmax = (unsigned long long*)(ws + 16777216);
        int* cnt  = (int*)(ws + 16793600);
        int* cand = (int*)(ws + 16801792);

        normalize_e<<<P, 256, 0, stream>>>(E, Abf, packmax, cnt);
        dim3 g1(P / BM, (V + BN - 1) / BN);
        gemm_argmax<<<g1, 256, 0, stream>>>(Abf, T, packmax, cnt, cand);
        rescore<<<P, 256, 0, stream>>>(E, T, packmax, cnt, cand, out);
    }
}

// Round 2
// 1997.407 us; speedup vs baseline: 1.4693x; 1.4693x over previous
//
#include <hip/hip_runtime.h>
#include <hip/hip_bf16.h>
#include <stdint.h>

// Problem constants
#define P 2048
#define V 50257
#define D 4096
#define CAP 512            // candidate slots per row (fp8 margin is wider)
#define MARGIN 1.0e-2f     // ~9 sigma of two-sided fp8 e4m3 dot error

#define BM 128
#define BN 128
#define BK 32              // bf16 slow-path K-step
#define BKF 128            // fp8 fast-path K-step (one MFMA K=128 per frag)

using frag_ab = __attribute__((ext_vector_type(8))) short;  // 8 bf16 (4 VGPRs)
using frag_cd = __attribute__((ext_vector_type(4))) float;  // 4 fp32 acc
using i32x4   = __attribute__((ext_vector_type(4))) int;
using i32x8   = __attribute__((ext_vector_type(8))) int;

__device__ __forceinline__ unsigned short f2bf(float f) {
    __hip_bfloat16 h = __float2bfloat16(f);
    return *(unsigned short*)&h;
}

// OCP e4m3 saturating RNE conversion (hand-rolled: no hip_fp8.h dependency)
__device__ __forceinline__ unsigned char f2e4m3(float f) {
    uint32_t u = __float_as_uint(f);
    unsigned char sign = (unsigned char)((u >> 24) & 0x80u);
    uint32_t a = u & 0x7FFFFFFFu;
    if (a >= 0x43E00000u) return sign | 0x7E;        // >=448 -> clamp to 448
    if (a < 0x3C800000u) {                           // <2^-6 -> subnormal
        float af = __uint_as_float(a);
        int q = __float2int_rn(af * 512.0f);         // RNE onto 2^-9 grid, 0..8
        return sign | (unsigned char)q;              // q==8 -> 0x08 == 2^-6
    }
    uint32_t r = a + 0x0007FFFFu + ((a >> 20) & 1u); // RNE into 3-bit mantissa
    int eb = (int)(r >> 23) - 127 + 7;
    uint32_t m = (r >> 20) & 7u;
    return sign | (unsigned char)((eb << 3) | m);
}

// monotone key: order of key == order of float (incl. negatives)
__device__ __forceinline__ uint32_t fkey(float f) {
    uint32_t u = __float_as_uint(f);
    return (u & 0x80000000u) ? ~u : (u | 0x80000000u);
}
__device__ __forceinline__ float key2f(uint32_t k) {
    uint32_t u = (k & 0x80000000u) ? (k ^ 0x80000000u) : ~k;
    return __uint_as_float(u);
}

#define GLD_LDS16(g, l) __builtin_amdgcn_global_load_lds(                      \
    (const __attribute__((address_space(1))) void*)(g),                        \
    (__attribute__((address_space(3))) void*)(l), 16, 0, 0)

// ---------------- normalize embeddings -> fp8 (x256), init state ------------
__global__ __launch_bounds__(256) void normalize_e8(
        const float* __restrict__ E, unsigned char* __restrict__ A8,
        unsigned long long* __restrict__ packmax, int* __restrict__ cnt) {
    const int p = blockIdx.x;
    const int t = threadIdx.x;
    const float* row = E + (size_t)p * D;

    float4 vals[4];
    float ss = 0.f;
#pragma unroll
    for (int c = 0; c < 4; c++) {
        vals[c] = ((const float4*)row)[c * 256 + t];
        ss += vals[c].x * vals[c].x + vals[c].y * vals[c].y
            + vals[c].z * vals[c].z + vals[c].w * vals[c].w;
    }
#pragma unroll
    for (int o = 1; o < 64; o <<= 1) ss += __shfl_xor(ss, o);
    __shared__ float wss[4];
    if ((t & 63) == 0) wss[t >> 6] = ss;
    __syncthreads();
    float tot = wss[0] + wss[1] + wss[2] + wss[3];
    float s = 256.0f / fmaxf(sqrtf(tot), 1e-8f);   // x256 pre-scale into e4m3 range

    unsigned char* dst = A8 + (size_t)p * D;
#pragma unroll
    for (int c = 0; c < 4; c++) {
        float4 v = vals[c];
        uint32_t b = (uint32_t)f2e4m3(v.x * s)
                   | ((uint32_t)f2e4m3(v.y * s) << 8)
                   | ((uint32_t)f2e4m3(v.z * s) << 16)
                   | ((uint32_t)f2e4m3(v.w * s) << 24);
        ((uint32_t*)dst)[c * 256 + t] = b;
    }
    if (t == 0) { packmax[p] = 0ull; cnt[p] = 0; }
}

// ---------------- normalize table row -> fp8 (x256) -------------------------
__global__ __launch_bounds__(256) void normalize_t8(
        const float* __restrict__ T, unsigned char* __restrict__ T8) {
    const int v = blockIdx.x;
    const int t = threadIdx.x;
    const float* row = T + (size_t)v * D;

    float4 vals[4];
    float ss = 0.f;
#pragma unroll
    for (int c = 0; c < 4; c++) {
        vals[c] = ((const float4*)row)[c * 256 + t];
        ss += vals[c].x * vals[c].x + vals[c].y * vals[c].y
            + vals[c].z * vals[c].z + vals[c].w * vals[c].w;
    }
#pragma unroll
    for (int o = 1; o < 64; o <<= 1) ss += __shfl_xor(ss, o);
    __shared__ float wss[4];
    if ((t & 63) == 0) wss[t >> 6] = ss;
    __syncthreads();
    float tot = wss[0] + wss[1] + wss[2] + wss[3];
    float s = 256.0f / fmaxf(sqrtf(tot), 1e-8f);

    unsigned char* dst = T8 + (size_t)v * D;
#pragma unroll
    for (int c = 0; c < 4; c++) {
        float4 x = vals[c];
        uint32_t b = (uint32_t)f2e4m3(x.x * s)
                   | ((uint32_t)f2e4m3(x.y * s) << 8)
                   | ((uint32_t)f2e4m3(x.z * s) << 16)
                   | ((uint32_t)f2e4m3(x.w * s) << 24);
        ((uint32_t*)dst)[c * 256 + t] = b;
    }
}

// ---------------- FAST PATH: MX-fp8 K=128 MFMA GEMM + argmax epilogue -------
// m148 port of the m97 structure: 128x128 tile, BKF=128, global_load_lds w16,
// 2-barrier loop. Scales all 1.0 (0x7F e8m0); data pre-scaled by 256 per side,
// scores rescaled by 2^-16 in the epilogue.
// Candidate list stores the full packed (fkey(score)<<32)|~idx key so rescore
// can filter against the FINAL max (stale-threshold appends are discarded).
__global__ __launch_bounds__(256) void gemm_fp8_argmax(
        const unsigned char* __restrict__ A8,   // [P][D] fp8 (normalized*256)
        const unsigned char* __restrict__ T8,   // [V][D] fp8 (normalized*256)
        unsigned long long* __restrict__ packmax,
        int* __restrict__ cnt, unsigned long long* __restrict__ cand) {
    __shared__ __align__(16) unsigned char As[BM * BKF];  // 16 KB
    __shared__ __align__(16) unsigned char Bs[BN * BKF];  // 16 KB

    const int t = threadIdx.x;
    const int m0 = blockIdx.x * BM;   // x fastest: 16 M-blocks share a B tile
    const int v0 = blockIdx.y * BN;
    const int lane = t & 63;
    const int w = t >> 6;
    const int wm = w & 1, wn = w >> 1;
    const int l15 = lane & 15, lq = lane >> 4;

    // staging: wave w stages rows [w*32, w*32+32) of A and B; 4 GLDs each.
    // GLD g writes 1024B at lds_base + lane*16 -> slot row = w*32+g*8+(lane>>3),
    // slot 16B-chunk = lane&7. Pre-swizzled source chunk = (lane&7) ^ (row&7).
    const int sr = lane >> 3;                 // row-within-8 (== row&7 of slot)
    const int sj = (lane & 7) ^ sr;           // swizzled source chunk
    const unsigned char* gA = A8 + (size_t)(m0 + w * 32 + sr) * D + sj * 16;
    const unsigned char* gB[4];
#pragma unroll
    for (int g = 0; g < 4; g++) {
        int r = v0 + w * 32 + g * 8 + sr;
        if (r > V - 1) r = V - 1;
        gB[g] = T8 + (size_t)r * D + sj * 16;
    }
    unsigned char* lA = As + w * 4096;
    unsigned char* lB = Bs + w * 4096;

    frag_cd acc[4][4] = {};

    for (int k0 = 0; k0 < D; k0 += BKF) {
        __syncthreads();   // previous iteration's fragment reads done
#pragma unroll
        for (int g = 0; g < 4; g++) {
            GLD_LDS16(gA + (size_t)g * 8 * D + k0, lA + g * 1024);
            GLD_LDS16(gB[g] + k0, lB + g * 1024);
        }
        __syncthreads();   // compiler drains vmcnt(0) before s_barrier

        // fragment: lane holds row=l15(+16i+64wm), k = lq*32..lq*32+31
        i32x8 af[4], bfr[4];
#pragma unroll
        for (int i = 0; i < 4; i++) {
            const int row = wm * 64 + i * 16 + l15;
            const int sw = (row & 7) << 4;
            const int base = row * BKF;
            i32x4 h0 = *(const i32x4*)&As[base + ((lq * 32) ^ sw)];
            i32x4 h1 = *(const i32x4*)&As[base + ((lq * 32 + 16) ^ sw)];
            af[i] = __builtin_shufflevector(h0, h1, 0, 1, 2, 3, 4, 5, 6, 7);
        }
#pragma unroll
        for (int j = 0; j < 4; j++) {
            const int row = wn * 64 + j * 16 + l15;
            const int sw = (row & 7) << 4;
            const int base = row * BKF;
            i32x4 h0 = *(const i32x4*)&Bs[base + ((lq * 32) ^ sw)];
            i32x4 h1 = *(const i32x4*)&Bs[base + ((lq * 32 + 16) ^ sw)];
            bfr[j] = __builtin_shufflevector(h0, h1, 0, 1, 2, 3, 4, 5, 6, 7);
        }
#pragma unroll
        for (int i = 0; i < 4; i++)
#pragma unroll
            for (int j = 0; j < 4; j++)
                acc[i][j] = __builtin_amdgcn_mfma_scale_f32_16x16x128_f8f6f4(
                    af[i], bfr[j], acc[i][j],
                    0, 0,                      // cbsz=fp8(e4m3), blgp=fp8(e4m3)
                    0, 0x7F7F7F7F,             // opsel_a, scale_a = 1.0 (e8m0)
                    0, 0x7F7F7F7F);            // opsel_b, scale_b = 1.0
    }

    // epilogue: rescale 2^-16, per embedding-row running max + candidate append
#pragma unroll
    for (int i = 0; i < 4; i++) {
#pragma unroll
        for (int r = 0; r < 4; r++) {
            const int p = m0 + wm * 64 + i * 16 + lq * 4 + r;  // C row = lq*4+reg
            float sc[4];
            int nidx[4];
            unsigned long long pks[4];
            unsigned long long best = 0ull;
#pragma unroll
            for (int j = 0; j < 4; j++) {
                int nl = wn * 64 + j * 16 + l15;               // C col = lane&15
                int n = v0 + nl;
                float s = -2.0f;
                if (n < V) s = acc[i][j][r] * 0x1p-16f;
                sc[j] = s; nidx[j] = n;
                unsigned long long pk = 0ull;
                if (n < V) {
                    pk = ((unsigned long long)fkey(s) << 32) |
                         (unsigned long long)(0xFFFFFFFFu - (uint32_t)n);
                    if (pk > best) best = pk;
                }
                pks[j] = pk;
            }
#pragma unroll
            for (int o = 1; o < 16; o <<= 1) {
                unsigned long long other = __shfl_xor(best, o);
                if (other > best) best = other;
            }
            unsigned long long oldpk = 0ull;
            if (l15 == 0) oldpk = atomicMax(packmax + p, best);
            oldpk = __shfl(oldpk, lane & 48);   // broadcast from group leader
            unsigned long long merged = best > oldpk ? best : oldpk;
            float thr = key2f((uint32_t)(merged >> 32)) - MARGIN;
#pragma unroll
            for (int j = 0; j < 4; j++) {
                if (nidx[j] < V && sc[j] >= thr) {
                    int slot = atomicAdd(cnt + p, 1);
                    if (slot < CAP) cand[(size_t)p * CAP + slot] = pks[j];
                }
            }
        }
    }
}

// ---------------- bf16 normalize_e (slow path only) -------------------------
__global__ __launch_bounds__(256) void normalize_e(
        const float* __restrict__ E, unsigned short* __restrict__ Abf,
        unsigned long long* __restrict__ packmax, int* __restrict__ cnt) {
    const int p = blockIdx.x;
    const int t = threadIdx.x;
    const float* row = E + (size_t)p * D;

    float4 vals[4];
    float ss = 0.f;
#pragma unroll
    for (int c = 0; c < 4; c++) {
        vals[c] = ((const float4*)row)[c * 256 + t];
        ss += vals[c].x * vals[c].x + vals[c].y * vals[c].y
            + vals[c].z * vals[c].z + vals[c].w * vals[c].w;
    }
#pragma unroll
    for (int o = 1; o < 64; o <<= 1) ss += __shfl_xor(ss, o);
    __shared__ float wss[4];
    if ((t & 63) == 0) wss[t >> 6] = ss;
    __syncthreads();
    float tot = wss[0] + wss[1] + wss[2] + wss[3];
    float inv = 1.0f / fmaxf(sqrtf(tot), 1e-8f);

    unsigned short* dst = Abf + (size_t)p * D;
#pragma unroll
    for (int c = 0; c < 4; c++) {
        float4 v = vals[c];
        uint2 st;
        st.x = (uint32_t)f2bf(v.x * inv) | ((uint32_t)f2bf(v.y * inv) << 16);
        st.y = (uint32_t)f2bf(v.z * inv) | ((uint32_t)f2bf(v.w * inv) << 16);
        ((uint2*)dst)[c * 256 + t] = st;
    }
    if (t == 0) { packmax[p] = 0ull; cnt[p] = 0; }
}

// ---------------- SLOW PATH (ws too small): fp32-table on-the-fly GEMM ------
__global__ __launch_bounds__(256) void gemm_argmax(
        const unsigned short* __restrict__ Abf,   // [P][D] bf16 (normalized)
        const float* __restrict__ T,              // [V][D] fp32
        unsigned long long* __restrict__ packmax,
        int* __restrict__ cnt, unsigned long long* __restrict__ cand) {
    __shared__ unsigned short As[BM * BK];
    __shared__ unsigned short Bs[BN * BK];
    __shared__ float invt[BN];

    const int t = threadIdx.x;
    const int m0 = blockIdx.x * BM;
    const int v0 = blockIdx.y * BN;
    const int lane = t & 63;
    const int wm = (t >> 6) & 1, wn = (t >> 6) >> 1;
    const int l15 = lane & 15, lq = lane >> 4;
    const int r0 = t >> 2, q0 = t & 3;

    frag_cd acc[4][4] = {};
    float ssq0 = 0.f, ssq1 = 0.f;

    for (int k0 = 0; k0 < D; k0 += BK) {
        uint4 areg[2];
        float4 b0[2], b1[2];
#pragma unroll
        for (int pass = 0; pass < 2; pass++) {
            int row = pass * 64 + r0;
            areg[pass] = *(const uint4*)(Abf + (size_t)(m0 + row) * D + k0 + q0 * 8);
            int v = v0 + row;
            if (v < V) {
                const float* src = T + (size_t)v * D + k0 + q0 * 8;
                b0[pass] = *(const float4*)src;
                b1[pass] = *(const float4*)(src + 4);
            } else {
                b0[pass] = float4{0.f, 0.f, 0.f, 0.f};
                b1[pass] = float4{0.f, 0.f, 0.f, 0.f};
            }
        }
        __syncthreads();
#pragma unroll
        for (int pass = 0; pass < 2; pass++) {
            *(uint4*)&As[(size_t)(pass * 256 + t) * 8] = areg[pass];
            float4 x = b0[pass], y = b1[pass];
            float s = x.x * x.x + x.y * x.y + x.z * x.z + x.w * x.w
                    + y.x * y.x + y.y * y.y + y.z * y.z + y.w * y.w;
            if (pass == 0) ssq0 += s; else ssq1 += s;
            uint4 bv;
            bv.x = (uint32_t)f2bf(x.x) | ((uint32_t)f2bf(x.y) << 16);
            bv.y = (uint32_t)f2bf(x.z) | ((uint32_t)f2bf(x.w) << 16);
            bv.z = (uint32_t)f2bf(y.x) | ((uint32_t)f2bf(y.y) << 16);
            bv.w = (uint32_t)f2bf(y.z) | ((uint32_t)f2bf(y.w) << 16);
            *(uint4*)&Bs[(size_t)(pass * 256 + t) * 8] = bv;
        }
        __syncthreads();

        frag_ab af[4], bf[4];
#pragma unroll
        for (int i = 0; i < 4; i++)
            af[i] = *(const frag_ab*)&As[(wm * 64 + i * 16 + l15) * BK + lq * 8];
#pragma unroll
        for (int j = 0; j < 4; j++)
            bf[j] = *(const frag_ab*)&Bs[(wn * 64 + j * 16 + l15) * BK + lq * 8];
#pragma unroll
        for (int i = 0; i < 4; i++)
#pragma unroll
            for (int j = 0; j < 4; j++)
                acc[i][j] = __builtin_amdgcn_mfma_f32_16x16x32_bf16(af[i], bf[j], acc[i][j], 0, 0, 0);
    }

    ssq0 += __shfl_xor(ssq0, 1); ssq0 += __shfl_xor(ssq0, 2);
    ssq1 += __shfl_xor(ssq1, 1); ssq1 += __shfl_xor(ssq1, 2);
    __syncthreads();
    if ((t & 3) == 0) {
        invt[r0]      = ssq0 > 0.f ? rsqrtf(ssq0) : 0.f;
        invt[64 + r0] = ssq1 > 0.f ? rsqrtf(ssq1) : 0.f;
    }
    __syncthreads();

#pragma unroll
    for (int i = 0; i < 4; i++) {
#pragma unroll
        for (int r = 0; r < 4; r++) {
            const int p = m0 + wm * 64 + i * 16 + lq * 4 + r;
            float sc[4];
            int nidx[4];
            unsigned long long pks[4];
            unsigned long long best = 0ull;
#pragma unroll
            for (int j = 0; j < 4; j++) {
                int nl = wn * 64 + j * 16 + l15;
                int n = v0 + nl;
                float s = -2.0f;
                if (n < V) s = acc[i][j][r] * invt[nl];
                sc[j] = s; nidx[j] = n;
                unsigned long long pk = 0ull;
                if (n < V) {
                    pk = ((unsigned long long)fkey(s) << 32) |
                         (unsigned long long)(0xFFFFFFFFu - (uint32_t)n);
                    if (pk > best) best = pk;
                }
                pks[j] = pk;
            }
#pragma unroll
            for (int o = 1; o < 16; o <<= 1) {
                unsigned long long other = __shfl_xor(best, o);
                if (other > best) best = other;
            }
            unsigned long long oldpk = 0ull;
            if (l15 == 0) oldpk = atomicMax(packmax + p, best);
            oldpk = __shfl(oldpk, lane & 48);
            unsigned long long merged = best > oldpk ? best : oldpk;
            float thr = key2f((uint32_t)(merged >> 32)) - MARGIN;
#pragma unroll
            for (int j = 0; j < 4; j++) {
                if (nidx[j] < V && sc[j] >= thr) {
                    int slot = atomicAdd(cnt + p, 1);
                    if (slot < CAP) cand[(size_t)p * CAP + slot] = pks[j];
                }
            }
        }
    }
}

// ---------------- exact fp64 rescore of filtered candidates -----------------
// Filter by the FINAL packed max before any expensive eval: only candidates
// whose stored fp8 score is within MARGIN of the final fp8 max can be the
// true argmax (two-sided error bound), the rest are stale-threshold junk.
__global__ __launch_bounds__(256) void rescore(
        const float* __restrict__ E, const float* __restrict__ T,
        const unsigned long long* __restrict__ packmax,
        const int* __restrict__ cnt, const unsigned long long* __restrict__ cand,
        int* __restrict__ out) {
    const int p = blockIdx.x;
    const int t = threadIdx.x;
    const int w = t >> 6, lane = t & 63;
    const float* e = E + (size_t)p * D;

    const int c = cnt[p];
    const bool overflow = c > CAP;
    const int ncand = overflow ? 0 : c;

    const unsigned long long pk = packmax[p];
    const uint32_t thrkey = fkey(key2f((uint32_t)(pk >> 32)) - MARGIN);

    // compact surviving candidates into LDS (max-key entry always included)
    __shared__ int nf;
    __shared__ unsigned long long flist[CAP + 1];
    if (t == 0) { nf = 1; flist[0] = pk; }
    __syncthreads();
    for (int idx = t; idx < ncand; idx += 256) {
        unsigned long long ck = cand[(size_t)p * CAP + idx];
        if ((uint32_t)(ck >> 32) >= thrkey && ck != pk) {
            int s = atomicAdd(&nf, 1);
            flist[s] = ck;
        }
    }
    __syncthreads();
    const int total = nf;

    double best_s = -3.0;
    int best_v = 0x7FFFFFFF;

    auto evalw = [&](int v) -> double {   // whole-wave fp64 cosine
        const float4* tr = (const float4*)(T + (size_t)v * D);
        const float4* e4 = (const float4*)e;
        double dot = 0.0, ss = 0.0;
        for (int i = lane; i < D / 4; i += 64) {
            float4 tv = tr[i];
            float4 ev = e4[i];
            dot += (double)ev.x * tv.x + (double)ev.y * tv.y
                 + (double)ev.z * tv.z + (double)ev.w * tv.w;
            ss  += (double)tv.x * tv.x + (double)tv.y * tv.y
                 + (double)tv.z * tv.z + (double)tv.w * tv.w;
        }
#pragma unroll
        for (int o = 1; o < 64; o <<= 1) {
            dot += __shfl_xor(dot, o);
            ss  += __shfl_xor(ss, o);
        }
        return dot / fmax(sqrt(ss), 1e-8);
    };
    auto consider = [&](int v, double s) {
        if (s > best_s || (s == best_s && v < best_v)) { best_s = s; best_v = v; }
    };

    if (!overflow) {
        for (int idx = w; idx < total; idx += 4) {
            unsigned long long ck = flist[idx];
            int v = (int)(0xFFFFFFFFu - (uint32_t)ck);
            consider(v, evalw(v));
        }
    } else {
        // statistical never-case safety net: exact full scan
        for (int v = w; v < V; v += 4) consider(v, evalw(v));
    }

    __shared__ double bs[4];
    __shared__ int bv[4];
    if (lane == 0) { bs[w] = best_s; bv[w] = best_v; }
    __syncthreads();
    if (t == 0) {
        double s = bs[0]; int v = bv[0];
#pragma unroll
        for (int i = 1; i < 4; i++)
            if (bs[i] > s || (bs[i] == s && bv[i] < v)) { s = bs[i]; v = bv[i]; }
        out[p] = v;
    }
}

// ---------------- Launch ----------------------------------------------------
extern "C" void kernel_launch(void* const* d_in, const int* in_sizes, int n_in,
                              void* d_out, int out_size, void* d_ws, size_t ws_size,
                              hipStream_t stream) {
    const float* E = (const float*)d_in[0];   // [2048,4096] fp32
    const float* T = (const float*)d_in[1];   // [50257,4096] fp32
    int* out = (int*)d_out;                   // [2048] int32 ids

    char* ws = (char*)d_ws;

    // fast-path ws layout (fp8):
    //  0           : T8       50257*4096   = 205,852,672
    //  205,852,672 : A8       2048*4096    =   8,388,608
    //  214,241,280 : packmax  2048*8       =      16,384
    //  214,257,664 : cnt      2048*4       =       8,192
    //  214,265,856 : cand64   2048*512*8   =   8,388,608
    //  total: 222,654,464
    const size_t FAST_WS = 222654464ull;

    if (ws_size >= FAST_WS) {
        unsigned char* T8 = (unsigned char*)ws;
        unsigned char* A8 = (unsigned char*)(ws + 205852672ull);
        unsigned long long* packmax = (unsigned long long*)(ws + 214241280ull);
        int* cnt  = (int*)(ws + 214257664ull);
        unsigned long long* cand = (unsigned long long*)(ws + 214265856ull);

        normalize_e8<<<P, 256, 0, stream>>>(E, A8, packmax, cnt);
        normalize_t8<<<V, 256, 0, stream>>>(T, T8);
        dim3 g1(P / BM, (V + BN - 1) / BN);   // x fastest: 16 M-blocks share B tile
        gemm_fp8_argmax<<<g1, 256, 0, stream>>>(A8, T8, packmax, cnt, cand);
        rescore<<<P, 256, 0, stream>>>(E, T, packmax, cnt, cand, out);
    } else {
        // slow path (ws >= ~26 MB): on-the-fly fp32 table conversion, bf16 MFMA
        unsigned short* Abf = (unsigned short*)ws;
        unsigned long long* packmax = (unsigned long long*)(ws + 16777216);
        int* cnt  = (int*)(ws + 16793600);
        unsigned long long* cand = (unsigned long long*)(ws + 16801792);

        normalize_e<<<P, 256, 0, stream>>>(E, Abf, packmax, cnt);
        dim3 g1(P / BM, (V + BN - 1) / BN);
        gemm_argmax<<<g1, 256, 0, stream>>>(Abf, T, packmax, cnt, cand);
        rescore<<<P, 256, 0, stream>>>(E, T, packmax, cnt, cand, out);
    }
}